// Round 11
// baseline (601.666 us; speedup 1.0000x reference)
//
#include <hip/hip_runtime.h>
#include <math.h>

// DGLJTNNDecoder: B=4096, L=16, H=256, LAT=64, V=800.
// R11: R10 + amdgpu_waves_per_eu(4,4) on k_scan. R10's VGPR-resident weights
// SPILLED (VGPR_Count pinned at 64 by the 8-waves/EU heuristic; WRITE_SIZE
// jumped 111->281MB = scratch traffic). Pinning 4 waves/EU gives the
// allocator the 128-VGPR budget so wz/wh actually stay resident.
// Outputs: (q_loss, p_loss, q_acc, p_acc) fp32.

typedef unsigned short u16;
typedef __attribute__((ext_vector_type(4))) float f4;
typedef __attribute__((ext_vector_type(4))) unsigned short u16x4;
typedef __attribute__((ext_vector_type(8))) unsigned short u16x8;
typedef __attribute__((ext_vector_type(8))) short s16x8;
typedef __attribute__((ext_vector_type(4))) float f32x4;

#define DEV static __device__ __forceinline__

DEV u16 f2b(float f) {
  unsigned u = __float_as_uint(f);
  u += 0x7fffu + ((u >> 16) & 1u);
  return (u16)(u >> 16);
}
DEV float b2f(u16 h) { return __uint_as_float(((unsigned)h) << 16); }
DEV void split2(float v, u16& hi, u16& lo) {
  hi = f2b(v);
  lo = f2b(v - b2f(hi));
}
DEV float fsig(float x) { return __builtin_amdgcn_rcpf(1.f + __expf(-x)); }
DEV float ftanh(float x) {
  const float e = __expf(2.f * x);
  return 1.f - 2.f * __builtin_amdgcn_rcpf(e + 1.f);
}

DEV void gld16(const void* g, void* l) {
  __builtin_amdgcn_global_load_lds((const __attribute__((address_space(1))) void*)g,
                                   (__attribute__((address_space(3))) void*)l, 16, 0, 0);
}

#define MFMA(a, b, c) __builtin_amdgcn_mfma_f32_16x16x32_bf16((a), (b), (c), 0, 0, 0)

// ---------------- 128x128 block-tile GEMM mainloop: C[128,128] = A[128,K] * B[128,K]^T
template <int GR, int GC, bool ASPL, bool BSPL>
DEV void mm128(const u16* __restrict__ Ah, const u16* __restrict__ Al,
               const u16* __restrict__ Bh, const u16* __restrict__ Bl,
               int K, u16* sm, f32x4* acc) {
  constexpr int MT = 8 / GR, NT = 8 / GC;
  const int tid = threadIdx.x;
  const int lane = tid & 63;
  const int wv = tid >> 6;
  const int wr = wv / GC, wc = wv % GC;
  const size_t rs = (size_t)K * 2;  // row bytes
  const size_t soff = (size_t)(tid >> 2) * rs + (size_t)((tid & 3) * 16);
  const char* gAh = (const char*)Ah + soff;
  const char* gBh = (const char*)Bh + soff;
  const char* gAl = nullptr;
  const char* gBl = nullptr;
  if constexpr (ASPL) gAl = (const char*)Al + soff;
  if constexpr (BSPL) gBl = (const char*)Bl + soff;
  char* L = (char*)sm;
  const int wb = wv * 1024;  // wave-uniform LDS chunk base
  const int frow = lane & 15, fkb = (lane >> 4) * 16;
  const char* rA = L + (size_t)((wr * 16 * MT + frow) * 64 + fkb);
  const char* rB = L + 8192 + (size_t)((wc * 16 * NT + frow) * 64 + fkb);
  const size_t rskip = rs * 64;
  const int nk = K >> 5;
  for (int kt = 0; kt < nk; ++kt) {
    gld16(gAh, L + wb);
    gld16(gAh + rskip, L + 4096 + wb);
    gld16(gBh, L + 8192 + wb);
    gld16(gBh + rskip, L + 12288 + wb);
    if constexpr (ASPL) {
      gld16(gAl, L + 16384 + wb);
      gld16(gAl + rskip, L + 20480 + wb);
    }
    if constexpr (BSPL) {
      gld16(gBl, L + 24576 + wb);
      gld16(gBl + rskip, L + 28672 + wb);
    }
    gAh += 64; gBh += 64;
    if constexpr (ASPL) gAl += 64;
    if constexpr (BSPL) gBl += 64;
    __syncthreads();
    s16x8 a_[MT], b_[NT];
#pragma unroll
    for (int i = 0; i < MT; ++i) a_[i] = *(const s16x8*)(rA + i * 1024);
#pragma unroll
    for (int j = 0; j < NT; ++j) b_[j] = *(const s16x8*)(rB + j * 1024);
#pragma unroll
    for (int i = 0; i < MT; ++i)
#pragma unroll
      for (int j = 0; j < NT; ++j)
        acc[i * NT + j] = MFMA(a_[i], b_[j], acc[i * NT + j]);
    if constexpr (BSPL) {
      s16x8 bl_[NT];
#pragma unroll
      for (int j = 0; j < NT; ++j) bl_[j] = *(const s16x8*)(rB + 16384 + j * 1024);
#pragma unroll
      for (int i = 0; i < MT; ++i)
#pragma unroll
        for (int j = 0; j < NT; ++j)
          acc[i * NT + j] = MFMA(a_[i], bl_[j], acc[i * NT + j]);
    }
    if constexpr (ASPL) {
      s16x8 al_[MT];
#pragma unroll
      for (int i = 0; i < MT; ++i) al_[i] = *(const s16x8*)(rA + 16384 + i * 1024);
#pragma unroll
      for (int i = 0; i < MT; ++i)
#pragma unroll
        for (int j = 0; j < NT; ++j)
          acc[i * NT + j] = MFMA(al_[i], b_[j], acc[i * NT + j]);
    }
    __syncthreads();
  }
}

// ---------------- weight packing (fp32 -> bf16 planes; hi-only where sufficient) ------
__global__ __launch_bounds__(256) void k_pack(const float* __restrict__ Wz, const float* __restrict__ Wr,
                                              const float* __restrict__ Ur, const float* __restrict__ Wh,
                                              const float* __restrict__ Ww, const float* __restrict__ Uw,
                                              const float* __restrict__ Wo, const float* __restrict__ emb,
                                              const float* __restrict__ tree,
                                              u16* wpk, u16* uzh, u16* urw, u16* wu, u16* wt2, u16* wov,
                                              u16* uxp2, u16* utp2, u16* embp, u16* tre2) {
  const int i = blockIdx.x * 256 + threadIdx.x;
  const int seg = blockIdx.y;
  u16 h, l;
  if (seg == 0) {  // wpk [768][256] hi+lo: x-side of Wz|Wh|Wr
    if (i >= 196608) return;
    const int row = i >> 8, c = i & 255;
    const float v = (row < 256) ? Wz[row * 512 + c]
                                : (row < 512) ? Wh[(row - 256) * 512 + c] : Wr[(row - 512) * 256 + c];
    split2(v, h, l); wpk[i] = h; wpk[196608 + i] = l;
  } else if (seg == 1) {  // uzh [512][256] hi only: m-side of Wz|Wh
    if (i >= 131072) return;
    const int row = i >> 8, c = i & 255;
    const float v = (row < 256) ? Wz[row * 512 + 256 + c] : Wh[(row - 256) * 512 + 256 + c];
    uzh[i] = f2b(v);
  } else if (seg == 2) {  // urw [256][256] hi only
    if (i >= 65536) return;
    urw[i] = f2b(Ur[i]);
  } else if (seg == 3) {  // wu rows 0-255 = Ww[:, :256] hi; wt2 [2][256][64] split
    if (i >= 81920) return;
    if (i < 65536) {
      const int row = i >> 8, c = i & 255;
      wu[i] = f2b(Ww[row * 320 + c]);
    } else {
      const int j = i - 65536, row = j >> 6, c = j & 63;
      split2(Ww[row * 320 + 256 + c], h, l); wt2[j] = h; wt2[16384 + j] = l;
    }
  } else if (seg == 4) {  // wov [896][256] hi only, rows 800.. zero
    if (i >= 229376) return;
    const float v = (i < 204800) ? Wo[i] : 0.f;
    wov[i] = f2b(v);
  } else if (seg == 5) {  // uxp2 split; wu rows 256-511 = Uw[:,256:512] hi; utp2 split
    if (i >= 147456) return;
    if (i < 65536) {
      const int row = i >> 8, c = i & 255;
      split2(Uw[row * 576 + c], h, l); uxp2[i] = h; uxp2[65536 + i] = l;
    } else if (i < 131072) {
      const int j = i - 65536, row = j >> 8, c = j & 255;
      wu[65536 + j] = f2b(Uw[row * 576 + 256 + c]);
    } else {
      const int j = i - 131072, row = j >> 6, c = j & 63;
      split2(Uw[row * 576 + 512 + c], h, l); utp2[j] = h; utp2[16384 + j] = l;
    }
  } else if (seg == 6) {  // embp [2][896][256] split, rows 800.. zero
    if (i >= 229376) return;
    const int row = i >> 8;
    const float v = (row < 800) ? emb[i] : 0.f;
    split2(v, h, l); embp[i] = h; embp[229376 + i] = l;
  } else {  // tre2 [2][4096][64] split
    if (i >= 65536) return;
    const int b = i >> 4, c4 = (i & 15) << 2;
    const f4 tv = *(const f4*)(tree + (size_t)b * 64 + c4);
    u16x4 hi, lo;
#pragma unroll
    for (int k = 0; k < 4; ++k) { u16 hh, ll; split2(tv[k], hh, ll); hi[k] = hh; lo[k] = ll; }
    *(u16x4*)(tre2 + (size_t)b * 64 + c4) = hi;
    *(u16x4*)(tre2 + 262144 + (size_t)b * 64 + c4) = lo;
  }
}

// ---------------- prep: 4 split GEMMs in one launch -----------------------------------
__global__ __launch_bounds__(256) void k_prep(const u16* __restrict__ embp, const u16* __restrict__ wpk,
                                              const u16* __restrict__ tre2, const u16* __restrict__ wt2,
                                              const u16* __restrict__ utp2, const u16* __restrict__ uxp2,
                                              u16* __restrict__ Aembh, float* __restrict__ Tq,
                                              float* __restrict__ Tp, float* __restrict__ Xp) {
  __shared__ u16 sm[16384];
  f32x4 acc[16] = {};
  const int bid = blockIdx.x;
  int seg, bx, by, K;
  const u16 *A0, *B0;
  size_t Aoff, Boff;
  if (bid < 42) { seg = 0; bx = bid % 7; by = bid / 7; A0 = embp; Aoff = 229376; B0 = wpk; Boff = 196608; K = 256; }
  else if (bid < 106) { const int l2 = bid - 42; seg = 1; bx = l2 % 32; by = l2 / 32; A0 = tre2; Aoff = 262144; B0 = wt2; Boff = 16384; K = 64; }
  else if (bid < 170) { const int l2 = bid - 106; seg = 2; bx = l2 % 32; by = l2 / 32; A0 = tre2; Aoff = 262144; B0 = utp2; Boff = 16384; K = 64; }
  else { const int l2 = bid - 170; seg = 3; bx = l2 % 7; by = l2 / 7; A0 = embp; Aoff = 229376; B0 = uxp2; Boff = 65536; K = 256; }
  A0 += (size_t)bx * 128 * K;
  B0 += (size_t)by * 128 * K;
  mm128<2, 2, true, true>(A0, A0 + Aoff, B0, B0 + Boff, K, sm, acc);
  const int lane = threadIdx.x & 63, wv = threadIdx.x >> 6;
  const int wr = wv >> 1, wc = wv & 1, quad = lane >> 4, c = lane & 15;
#pragma unroll
  for (int i = 0; i < 4; ++i)
#pragma unroll
    for (int j = 0; j < 4; ++j)
#pragma unroll
      for (int rg = 0; rg < 4; ++rg) {
        const size_t row = (size_t)bx * 128 + wr * 64 + i * 16 + quad * 4 + rg;
        const int col = by * 128 + wc * 64 + j * 16 + c;
        const float v = acc[i * 4 + j][rg];
        if (seg == 0) Aembh[row * 768 + col] = f2b(v);
        else if (seg == 1) Tq[row * 256 + col] = v;
        else if (seg == 2) Tp[row * 256 + col] = v;
        else Xp[row * 256 + col] = v;
      }
}

// ---------------- fused GRU scan: 256 blocks x 1024 thr; Uz/Uh resident in VGPRs ------
// amdgpu_waves_per_eu(4,4): pins the allocator at 4 waves/EU -> 128-VGPR budget,
// so the 64 VGPRs of weight fragments stay resident (R10 spilled them at 64).
__global__ __launch_bounds__(1024, 1) __attribute__((amdgpu_waves_per_eu(4, 4)))
void k_scan(const u16* __restrict__ uzh, const u16* __restrict__ urw,
            const u16* __restrict__ Aembh, const int* __restrict__ wid,
            const float* __restrict__ Wz_b, const float* __restrict__ Wh_b,
            const float* __restrict__ Ur_b,
            u16* __restrict__ mfh, u16* __restrict__ mrh) {
  __shared__ __align__(16) u16 MH[8192];
  __shared__ __align__(16) u16 ML[8192];
  __shared__ __align__(16) u16 RH[8192];
  __shared__ __align__(16) u16 RL[8192];
  const int tid = threadIdx.x;
  const int wv = tid >> 6, lane = tid & 63;
  const int l15 = lane & 15, quad = lane >> 4;
  const int r0 = blockIdx.x * 32;
  const int dir = r0 >> 12;
  const int b0 = r0 & 4095;
  for (int i = tid; i < 8192; i += 1024) { MH[i] = 0; ML[i] = 0; RH[i] = 0; RL[i] = 0; }
  const int zc0 = wv * 16;
  const int cc = zc0 + l15;
  const float bzv = Wz_b[cc], bhv = Wh_b[cc], urv = Ur_b[cc];
  // ---- step-invariant weight fragments -> VGPRs (64 VGPRs) ----
  s16x8 wz[8], wh[8];
#pragma unroll
  for (int kc = 0; kc < 8; ++kc) {
    const size_t zo = (size_t)cc * 256 + kc * 32 + quad * 8;
    wz[kc] = *(const s16x8*)(uzh + zo);
    wh[kc] = *(const s16x8*)(uzh + zo + 65536);
  }
  float mnew[2][4];
  __syncthreads();
  for (int s = 0; s < 15; ++s) {
    // ---- prefetch this step's gather indices (hides wid L2 latency) ----
    const int tsrc = dir ? (15 - s) : s;
    const int tdst = dir ? (14 - s) : (s + 1);
    int xids[8], xds[8];
#pragma unroll
    for (int mt = 0; mt < 2; ++mt)
#pragma unroll
      for (int rg = 0; rg < 4; ++rg) {
        const int b = b0 + mt * 16 + quad * 4 + rg;
        xids[mt * 4 + rg] = wid[b * 16 + tsrc];
        xds[mt * 4 + rg] = (s < 14) ? wid[b * 16 + tdst] : 0;
      }
    // ---- phase A: z-pre = m @ Uz^T, h-pre = rm @ Uh^T (weights from VGPRs) ----
    f32x4 aZ[2] = {};
    f32x4 aH[2] = {};
    for (int kc = 0; kc < 8; ++kc) {
      s16x8 amh[2], aml[2], arh[2], arl[2];
#pragma unroll
      for (int mt = 0; mt < 2; ++mt) {
        const int ai = ((kc * 4 + quad) * 32 + mt * 16 + l15) * 8;
        amh[mt] = *(const s16x8*)&MH[ai];
        aml[mt] = *(const s16x8*)&ML[ai];
        arh[mt] = *(const s16x8*)&RH[ai];
        arl[mt] = *(const s16x8*)&RL[ai];
      }
#pragma unroll
      for (int mt = 0; mt < 2; ++mt) {
        aZ[mt] = MFMA(amh[mt], wz[kc], aZ[mt]);
        aZ[mt] = MFMA(aml[mt], wz[kc], aZ[mt]);
        aH[mt] = MFMA(arh[mt], wh[kc], aH[mt]);
        aH[mt] = MFMA(arl[mt], wh[kc], aH[mt]);
      }
    }
    __syncthreads();
    // ---- elem: z, h_til, m update ----
#pragma unroll
    for (int mt = 0; mt < 2; ++mt)
#pragma unroll
      for (int rg = 0; rg < 4; ++rg) {
        const int rr = mt * 16 + quad * 4 + rg;
        const int xid = xids[mt * 4 + rg];
        const int mi = ((cc >> 3) * 32 + rr) * 8 + (cc & 7);
        const float az = b2f(Aembh[(size_t)xid * 768 + cc]);
        const float ah = b2f(Aembh[(size_t)xid * 768 + 256 + cc]);
        const float mp = b2f(MH[mi]) + b2f(ML[mi]);
        const float z = fsig(aZ[mt][rg] + az + bzv);
        const float ht = ftanh(aH[mt][rg] + ah + bhv);
        const float mv = (1.f - z) * mp + z * ht;
        mnew[mt][rg] = mv;
        u16 hh, ll; split2(mv, hh, ll);
        MH[mi] = hh; ML[mi] = ll;
      }
    __syncthreads();
    // ---- coalesced copy of MH -> global hi-plane (mf fwd / mr rev) ----
    {
      u16* dst = dir ? (mrh + ((size_t)(14 - s) * 4096 + b0) * 256)
                     : (mfh + ((size_t)s * 4096 + b0) * 256);
      const int r = tid >> 5, cg = tid & 31;
      const s16x8 v = *(const s16x8*)&MH[(cg * 32 + r) * 8];
      *(s16x8*)(dst + r * 256 + cg * 8) = v;
    }
    if (s == 14) break;
    // ---- phase B: rm = sigmoid(m_new @ Ur^T + Aemb_r[dst] + Ur_b) * m_new ----
    f32x4 aR[2] = {};
    for (int kc = 0; kc < 8; ++kc) {
      s16x8 amh[2], aml[2];
#pragma unroll
      for (int mt = 0; mt < 2; ++mt) {
        const int ai = ((kc * 4 + quad) * 32 + mt * 16 + l15) * 8;
        amh[mt] = *(const s16x8*)&MH[ai];
        aml[mt] = *(const s16x8*)&ML[ai];
      }
      const size_t ro = (size_t)cc * 256 + kc * 32 + quad * 8;
      const s16x8 brh = *(const s16x8*)(urw + ro);
#pragma unroll
      for (int mt = 0; mt < 2; ++mt) {
        aR[mt] = MFMA(amh[mt], brh, aR[mt]);
        aR[mt] = MFMA(aml[mt], brh, aR[mt]);
      }
    }
#pragma unroll
    for (int mt = 0; mt < 2; ++mt)
#pragma unroll
      for (int rg = 0; rg < 4; ++rg) {
        const int rr = mt * 16 + quad * 4 + rg;
        const int xd = xds[mt * 4 + rg];
        const int mi = ((cc >> 3) * 32 + rr) * 8 + (cc & 7);
        const float ar = b2f(Aembh[(size_t)xd * 768 + 512 + cc]);
        const float rp = aR[mt][rg] + ar + urv;
        const float rmv = fsig(rp) * mnew[mt][rg];
        u16 hh, ll; split2(rmv, hh, ll);
        RH[mi] = hh; RL[mi] = ll;
      }
    __syncthreads();
  }
}

// ---------------- mid: heads1 (q1 + pH-fwd fused GEMM) + build_hrev + roots -----------
__global__ __launch_bounds__(256) void k_mid(const u16* __restrict__ mfh, const u16* __restrict__ mrh,
                                             const u16* __restrict__ wu,
                                             const float* __restrict__ Tq, const float* __restrict__ W_b,
                                             const float* __restrict__ Xp, const float* __restrict__ Tp,
                                             const float* __restrict__ U_b, const float* __restrict__ Us_w,
                                             const int* __restrict__ wid,
                                             u16* __restrict__ hq, u16* __restrict__ hrev,
                                             float* __restrict__ ppart) {
  const int bid = blockIdx.x;
  const int tid = threadIdx.x;
  if (bid < 1920) {
    __shared__ u16 sm[8192];
    f32x4 acc[16] = {};
    const int rb = bid >> 2, ct = bid & 3;
    const u16* Ah = mfh + (size_t)rb * 128 * 256;
    const u16* Bh = wu + (size_t)ct * 128 * 256;
    mm128<4, 1, false, false>(Ah, nullptr, Bh, nullptr, 256, sm, acc);
    const int lane = tid & 63, wv = tid >> 6, quad = lane >> 4, c = lane & 15;
    if (ct < 2) {
      const int colb = ct * 128;
#pragma unroll
      for (int i = 0; i < 2; ++i)
#pragma unroll
        for (int rg = 0; rg < 4; ++rg) {
          const size_t row = (size_t)rb * 128 + wv * 32 + i * 16 + quad * 4 + rg;
          const int b = (int)(row & 4095);
#pragma unroll
          for (int j = 0; j < 8; ++j) {
            const int col = colb + j * 16 + c;
            const float hv = fmaxf(acc[i * 8 + j][rg] + Tq[(size_t)b * 256 + col] + W_b[col], 0.f);
            hq[(row + 4096) * 256 + col] = f2b(hv);
          }
        }
    } else {
      const int colb = (ct - 2) * 128;
#pragma unroll
      for (int i = 0; i < 2; ++i)
#pragma unroll
        for (int rg = 0; rg < 4; ++rg) {
          const size_t row = (size_t)rb * 128 + wv * 32 + i * 16 + quad * 4 + rg;
          const int t = (int)(row >> 12), b = (int)(row & 4095);
          const int xid = wid[b * 16 + t + 1];
          const int prow = (int)row + 4096;
          float d = 0.f;
#pragma unroll
          for (int j = 0; j < 8; ++j) {
            const int col = colb + j * 16 + c;
            float h = acc[i * 8 + j][rg] + Xp[(size_t)xid * 256 + col] + Tp[(size_t)b * 256 + col] + U_b[col];
            h = fmaxf(h, 0.f);
            d += h * Us_w[col];
          }
#pragma unroll
          for (int dd = 1; dd < 16; dd <<= 1) d += __shfl_xor(d, dd);
          if (c == 0) ppart[(size_t)prow * 2 + (ct - 2)] = d;
        }
    }
  } else if (bid < 9600) {
    const int idx = (bid - 1920) * 256 + tid;  // < 61440*32
    const int r = idx >> 5, g8 = idx & 31;
    const int t = r >> 12;
    const size_t o = (size_t)r * 256 + g8 * 8;
    const u16x8 a = *(const u16x8*)(mrh + o);
    u16x8 out = a;
    if (t > 0) {
      const u16x8 a2 = *(const u16x8*)(mfh + o - 1048576);  // (t-1)*4096 rows earlier
#pragma unroll
      for (int k = 0; k < 8; ++k) out[k] = f2b(b2f(a[k]) + b2f(a2[k]));
    }
    *(u16x8*)(hrev + o) = out;
  } else {
    const int b = bid - 9600;  // < 4096
    const int col = tid;
    const float hv = fmaxf(Tq[(size_t)b * 256 + col] + W_b[col], 0.f);
    hq[(size_t)b * 256 + col] = f2b(hv);
    const int xid = wid[b * 16];
    float d = fmaxf(Xp[(size_t)xid * 256 + col] + Tp[(size_t)b * 256 + col] + U_b[col], 0.f) * Us_w[col];
#pragma unroll
    for (int dd = 1; dd < 64; dd <<= 1) d += __shfl_xor(d, dd);
    __shared__ float red[4];
    if ((tid & 63) == 0) red[tid >> 6] = d;
    __syncthreads();
    if (tid == 0) {
      ppart[(size_t)b * 2] = red[0] + red[1] + red[2] + red[3];
      ppart[(size_t)b * 2 + 1] = 0.f;
    }
  }
}

// ---------------- tail: q2 (logits+softmax partials) + pH-rev -------------------------
__global__ __launch_bounds__(256) void k_tail(const u16* __restrict__ hq, const u16* __restrict__ wov,
                                              const u16* __restrict__ wu, const u16* __restrict__ hrev,
                                              const float* __restrict__ Wo_b, const float* __restrict__ Xp,
                                              const float* __restrict__ Tp, const float* __restrict__ U_b,
                                              const float* __restrict__ Us_w, const int* __restrict__ wid,
                                              float* __restrict__ qpart, float* __restrict__ ppart) {
  __shared__ u16 sm[8192];
  f32x4 acc[16] = {};
  const int bid = blockIdx.x;
  const int tid = threadIdx.x, lane = tid & 63, wv = tid >> 6;
  const int quad = lane >> 4, c = lane & 15;
  if (bid < 3584) {
    const int by = bid % 7, bx = bid / 7;
    const u16* Ah = hq + (size_t)bx * 128 * 256;
    const u16* Bh = wov + (size_t)by * 128 * 256;
    mm128<4, 1, false, false>(Ah, nullptr, Bh, nullptr, 256, sm, acc);
    const int colb = by * 128;
#pragma unroll
    for (int i = 0; i < 2; ++i)
#pragma unroll
      for (int rg = 0; rg < 4; ++rg) {
        const size_t row = (size_t)bx * 128 + wv * 32 + i * 16 + quad * 4 + rg;
        const int t = (int)(row >> 12), b = (int)(row & 4095);
        const int qt = wid[b * 16 + t];
        float vals[8];
        float mx = -1e30f;
        int am = 0x7fffffff;
#pragma unroll
        for (int j = 0; j < 8; ++j) {
          const int col = colb + j * 16 + c;
          float v = -1e30f;
          if (col < 800) v = acc[i * 8 + j][rg] + Wo_b[col];
          vals[j] = v;
          if (v > mx) { mx = v; am = col; }
        }
        float gm = mx;
        int ga = am;
#pragma unroll
        for (int d = 1; d < 16; d <<= 1) {
          const float om = __shfl_xor(gm, d);
          const int oa = __shfl_xor(ga, d);
          if (om > gm || (om == gm && oa < ga)) { gm = om; ga = oa; }
        }
        float s = 0.f, sel = -1e30f;
#pragma unroll
        for (int j = 0; j < 8; ++j) {
          s += __expf(vals[j] - gm);
          const int col = colb + j * 16 + c;
          if (col == qt) sel = vals[j];
        }
#pragma unroll
        for (int d = 1; d < 16; d <<= 1) {
          s += __shfl_xor(s, d);
          sel = fmaxf(sel, __shfl_xor(sel, d));
        }
        if (c == 0) {
          f4 o;
          o.x = gm; o.y = s; o.z = (float)ga; o.w = sel;
          *(f4*)(qpart + (row * 8 + by) * 4) = o;
        }
      }
  } else {
    const int l2 = bid - 3584;
    const int by = l2 & 1, bx = l2 >> 1;
    const u16* Ah = hrev + (size_t)bx * 128 * 256;
    const u16* Bh = wu + (size_t)(256 + by * 128) * 256;
    mm128<4, 1, false, false>(Ah, nullptr, Bh, nullptr, 256, sm, acc);
    const int colb = by * 128;
#pragma unroll
    for (int i = 0; i < 2; ++i)
#pragma unroll
      for (int rg = 0; rg < 4; ++rg) {
        const size_t row = (size_t)bx * 128 + wv * 32 + i * 16 + quad * 4 + rg;
        const int t = (int)(row >> 12), b = (int)(row & 4095);
        const int xid = wid[b * 16 + t];
        const int prow = (30 - t) * 4096 + b;
        float d = 0.f;
#pragma unroll
        for (int j = 0; j < 8; ++j) {
          const int col = colb + j * 16 + c;
          float h = acc[i * 8 + j][rg] + Xp[(size_t)xid * 256 + col] + Tp[(size_t)b * 256 + col] + U_b[col];
          h = fmaxf(h, 0.f);
          d += h * Us_w[col];
        }
#pragma unroll
        for (int dd = 1; dd < 16; dd <<= 1) d += __shfl_xor(d, dd);
        if (c == 0) ppart[(size_t)prow * 2 + by] = d;
      }
  }
}

// ---------------- reduce: q (merge 7 partials) + p (logistic loss) --------------------
__global__ __launch_bounds__(256) void k_red(const float* __restrict__ qpart, const float* __restrict__ ppart,
                                             const int* __restrict__ wid, const float* __restrict__ Us_b,
                                             float* __restrict__ accb) {
  __shared__ float s0, s1;
  if (threadIdx.x == 0) { s0 = 0.f; s1 = 0.f; }
  __syncthreads();
  if (blockIdx.x < 256) {
    const int r = blockIdx.x * 256 + threadIdx.x;  // < 65536
    f4 parts[7];
#pragma unroll
    for (int i = 0; i < 7; ++i) parts[i] = *(const f4*)(qpart + ((size_t)r * 8 + i) * 4);
    float M = -1e30f;
    int am = 0x7fffffff;
#pragma unroll
    for (int i = 0; i < 7; ++i) {
      const float m_ = parts[i].x;
      const int a_ = (int)parts[i].z;
      if (m_ > M || (m_ == M && a_ < am)) { M = m_; am = a_; }
    }
    float S = 0.f, sel = -1e30f;
#pragma unroll
    for (int i = 0; i < 7; ++i) {
      S += parts[i].y * __expf(parts[i].x - M);
      sel = fmaxf(sel, parts[i].w);
    }
    const float logZ = M + logf(S);
    const int t = r >> 12, b = r & 4095;
    const int qt = wid[b * 16 + t];
    atomicAdd(&s0, logZ - sel);
    atomicAdd(&s1, (am == qt) ? 1.f : 0.f);
    __syncthreads();
    if (threadIdx.x == 0) {
      atomicAdd(&accb[blockIdx.x & 15], s0);
      atomicAdd(&accb[16 + (blockIdx.x & 15)], s1);
    }
  } else {
    const int r = (blockIdx.x - 256) * 256 + threadIdx.x;  // < 126976
    const float p = ppart[(size_t)r * 2] + ppart[(size_t)r * 2 + 1] + Us_b[0];
    const int sidx = r >> 12;
    const float pt = (sidx < 15) ? 1.f : 0.f;
    const float loss = fmaxf(p, 0.f) + log1pf(expf(-fabsf(p))) - p * pt;
    const float hit = ((p > 0.f) == (pt > 0.5f)) ? 1.f : 0.f;
    atomicAdd(&s0, loss);
    atomicAdd(&s1, hit);
    __syncthreads();
    if (threadIdx.x == 0) {
      atomicAdd(&accb[32 + (blockIdx.x & 15)], s0);
      atomicAdd(&accb[48 + (blockIdx.x & 15)], s1);
    }
  }
}

__global__ void k_finalize(const float* __restrict__ accb, float* __restrict__ out) {
  if (threadIdx.x == 0 && blockIdx.x == 0) {
    float ql = 0, qa = 0, pl = 0, pa = 0;
    for (int i = 0; i < 16; ++i) {
      ql += accb[i];
      qa += accb[16 + i];
      pl += accb[32 + i];
      pa += accb[48 + i];
    }
    out[0] = ql / 4096.f;
    out[1] = pl / 4096.f;
    out[2] = qa / 65536.f;
    out[3] = pa / 126976.f;
  }
}

__global__ void k_flag(float* __restrict__ out) {
  if (threadIdx.x < 4) out[threadIdx.x] = -12345.f;  // ws_size-too-small sentinel
}

// ---------------- host launch ---------------------------------------------------------
extern "C" void kernel_launch(void* const* d_in, const int* in_sizes, int n_in,
                              void* d_out, int out_size, void* d_ws, size_t ws_size,
                              hipStream_t stream) {
  (void)in_sizes; (void)n_in; (void)out_size;
  const int* wid = (const int*)d_in[0];
  const float* tree = (const float*)d_in[1];
  const float* emb = (const float*)d_in[2];
  const float* Wz_w = (const float*)d_in[3];
  const float* Wz_b = (const float*)d_in[4];
  const float* Wr_w = (const float*)d_in[5];
  const float* Ur_w = (const float*)d_in[6];
  const float* Ur_b = (const float*)d_in[7];
  const float* Wh_w = (const float*)d_in[8];
  const float* Wh_b = (const float*)d_in[9];
  const float* W_w = (const float*)d_in[10];
  const float* W_b = (const float*)d_in[11];
  const float* U_w = (const float*)d_in[12];
  const float* U_b = (const float*)d_in[13];
  const float* Wo_w = (const float*)d_in[14];
  const float* Wo_b = (const float*)d_in[15];
  const float* Us_w = (const float*)d_in[16];
  const float* Us_b = (const float*)d_in[17];
  char* ws = (char*)d_ws;

  constexpr size_t NEED = 152273152ull;  // ~145.2 MB
  if (ws_size < NEED) {
    k_flag<<<1, 64, 0, stream>>>((float*)d_out);
    return;
  }

  u16* hq = (u16*)(ws + 0ull);                 // [65536][256]
  u16* hrev = (u16*)(ws + 33554432ull);        // [61440][256]
  u16* mfh = (u16*)(ws + 65011712ull);         // [61440][256]
  u16* mrh = (u16*)(ws + 96468992ull);         // [61440][256]
  u16* Aembh = (u16*)(ws + 127926272ull);      // [896][768] hi
  u16* embp = (u16*)(ws + 129302528ull);       // [2][896][256]
  u16* wpk = (u16*)(ws + 130220032ull);        // [2][768][256]
  u16* uzh = (u16*)(ws + 131006464ull);        // [512][256] hi
  u16* urw = (u16*)(ws + 131268608ull);        // [256][256] hi
  u16* wu = (u16*)(ws + 131399680ull);         // [512][256] hi: Ww | Uh
  u16* wt2 = (u16*)(ws + 131661824ull);        // [2][256][64]
  u16* wov = (u16*)(ws + 131727360ull);        // [896][256] hi
  u16* uxp2 = (u16*)(ws + 132186112ull);       // [2][256][256]
  u16* utp2 = (u16*)(ws + 132448256ull);       // [2][256][64]
  u16* tre2 = (u16*)(ws + 132513792ull);       // [2][4096][64]
  float* Tq = (float*)(ws + 133562368ull);     // [4096][256]
  float* Tp = (float*)(ws + 137756672ull);     // [4096][256]
  float* Xp = (float*)(ws + 141950976ull);     // [896][256]
  float* qpart = (float*)(ws + 142868480ull);  // [65536][8] f4
  float* ppart = (float*)(ws + 151257088ull);  // [126976][2]
  float* accb = (float*)(ws + 152272896ull);   // 64 floats

  hipMemsetAsync(accb, 0, 256, stream);

  k_pack<<<dim3(896, 8), 256, 0, stream>>>(Wz_w, Wr_w, Ur_w, Wh_w, W_w, U_w, Wo_w, emb, tree,
                                           wpk, uzh, urw, wu, wt2, wov, uxp2, utp2, embp, tre2);
  k_prep<<<184, 256, 0, stream>>>(embp, wpk, tre2, wt2, utp2, uxp2, Aembh, Tq, Tp, Xp);
  k_scan<<<256, 1024, 0, stream>>>(uzh, urw, Aembh, wid, Wz_b, Wh_b, Ur_b, mfh, mrh);
  k_mid<<<13696, 256, 0, stream>>>(mfh, mrh, wu, Tq, W_b, Xp, Tp, U_b, Us_w, wid, hq, hrev, ppart);
  k_tail<<<4544, 256, 0, stream>>>(hq, wov, wu, hrev, Wo_b, Xp, Tp, U_b, Us_w, wid, qpart, ppart);
  k_red<<<752, 256, 0, stream>>>(qpart, ppart, wid, Us_b, accb);
  k_finalize<<<1, 64, 0, stream>>>(accb, (float*)d_out);
}

// Round 12
// 559.881 us; speedup vs baseline: 1.0746x; 1.0746x over previous
//
#include <hip/hip_runtime.h>
#include <math.h>

// DGLJTNNDecoder: B=4096, L=16, H=256, LAT=64, V=800.
// R12: k_scan reverted to R10 (waves_per_eu attr was ignored - VGPR pinned 64).
// q2 restructured: 512 A-resident blocks (A tile staged once into 64KB LDS,
// 7 Wo tiles streamed through 16KB dbuf), softmax partials merged in-register
// -> A L2 traffic 458->33MB, qpart 8x smaller, k_red q-branch trivial.
// Outputs: (q_loss, p_loss, q_acc, p_acc) fp32.

typedef unsigned short u16;
typedef __attribute__((ext_vector_type(4))) float f4;
typedef __attribute__((ext_vector_type(4))) unsigned short u16x4;
typedef __attribute__((ext_vector_type(8))) unsigned short u16x8;
typedef __attribute__((ext_vector_type(8))) short s16x8;
typedef __attribute__((ext_vector_type(4))) float f32x4;

#define DEV static __device__ __forceinline__

DEV u16 f2b(float f) {
  unsigned u = __float_as_uint(f);
  u += 0x7fffu + ((u >> 16) & 1u);
  return (u16)(u >> 16);
}
DEV float b2f(u16 h) { return __uint_as_float(((unsigned)h) << 16); }
DEV void split2(float v, u16& hi, u16& lo) {
  hi = f2b(v);
  lo = f2b(v - b2f(hi));
}
DEV float fsig(float x) { return __builtin_amdgcn_rcpf(1.f + __expf(-x)); }
DEV float ftanh(float x) {
  const float e = __expf(2.f * x);
  return 1.f - 2.f * __builtin_amdgcn_rcpf(e + 1.f);
}

DEV void gld16(const void* g, void* l) {
  __builtin_amdgcn_global_load_lds((const __attribute__((address_space(1))) void*)g,
                                   (__attribute__((address_space(3))) void*)l, 16, 0, 0);
}

#define MFMA(a, b, c) __builtin_amdgcn_mfma_f32_16x16x32_bf16((a), (b), (c), 0, 0, 0)

// ---------------- 128x128 block-tile GEMM mainloop: C[128,128] = A[128,K] * B[128,K]^T
template <int GR, int GC, bool ASPL, bool BSPL>
DEV void mm128(const u16* __restrict__ Ah, const u16* __restrict__ Al,
               const u16* __restrict__ Bh, const u16* __restrict__ Bl,
               int K, u16* sm, f32x4* acc) {
  constexpr int MT = 8 / GR, NT = 8 / GC;
  const int tid = threadIdx.x;
  const int lane = tid & 63;
  const int wv = tid >> 6;
  const int wr = wv / GC, wc = wv % GC;
  const size_t rs = (size_t)K * 2;  // row bytes
  const size_t soff = (size_t)(tid >> 2) * rs + (size_t)((tid & 3) * 16);
  const char* gAh = (const char*)Ah + soff;
  const char* gBh = (const char*)Bh + soff;
  const char* gAl = nullptr;
  const char* gBl = nullptr;
  if constexpr (ASPL) gAl = (const char*)Al + soff;
  if constexpr (BSPL) gBl = (const char*)Bl + soff;
  char* L = (char*)sm;
  const int wb = wv * 1024;  // wave-uniform LDS chunk base
  const int frow = lane & 15, fkb = (lane >> 4) * 16;
  const char* rA = L + (size_t)((wr * 16 * MT + frow) * 64 + fkb);
  const char* rB = L + 8192 + (size_t)((wc * 16 * NT + frow) * 64 + fkb);
  const size_t rskip = rs * 64;
  const int nk = K >> 5;
  for (int kt = 0; kt < nk; ++kt) {
    gld16(gAh, L + wb);
    gld16(gAh + rskip, L + 4096 + wb);
    gld16(gBh, L + 8192 + wb);
    gld16(gBh + rskip, L + 12288 + wb);
    if constexpr (ASPL) {
      gld16(gAl, L + 16384 + wb);
      gld16(gAl + rskip, L + 20480 + wb);
    }
    if constexpr (BSPL) {
      gld16(gBl, L + 24576 + wb);
      gld16(gBl + rskip, L + 28672 + wb);
    }
    gAh += 64; gBh += 64;
    if constexpr (ASPL) gAl += 64;
    if constexpr (BSPL) gBl += 64;
    __syncthreads();
    s16x8 a_[MT], b_[NT];
#pragma unroll
    for (int i = 0; i < MT; ++i) a_[i] = *(const s16x8*)(rA + i * 1024);
#pragma unroll
    for (int j = 0; j < NT; ++j) b_[j] = *(const s16x8*)(rB + j * 1024);
#pragma unroll
    for (int i = 0; i < MT; ++i)
#pragma unroll
      for (int j = 0; j < NT; ++j)
        acc[i * NT + j] = MFMA(a_[i], b_[j], acc[i * NT + j]);
    if constexpr (BSPL) {
      s16x8 bl_[NT];
#pragma unroll
      for (int j = 0; j < NT; ++j) bl_[j] = *(const s16x8*)(rB + 16384 + j * 1024);
#pragma unroll
      for (int i = 0; i < MT; ++i)
#pragma unroll
        for (int j = 0; j < NT; ++j)
          acc[i * NT + j] = MFMA(a_[i], bl_[j], acc[i * NT + j]);
    }
    if constexpr (ASPL) {
      s16x8 al_[MT];
#pragma unroll
      for (int i = 0; i < MT; ++i) al_[i] = *(const s16x8*)(rA + 16384 + i * 1024);
#pragma unroll
      for (int i = 0; i < MT; ++i)
#pragma unroll
        for (int j = 0; j < NT; ++j)
          acc[i * NT + j] = MFMA(al_[i], b_[j], acc[i * NT + j]);
    }
    __syncthreads();
  }
}

// ---------------- weight packing (fp32 -> bf16 planes; hi-only where sufficient) ------
__global__ __launch_bounds__(256) void k_pack(const float* __restrict__ Wz, const float* __restrict__ Wr,
                                              const float* __restrict__ Ur, const float* __restrict__ Wh,
                                              const float* __restrict__ Ww, const float* __restrict__ Uw,
                                              const float* __restrict__ Wo, const float* __restrict__ emb,
                                              const float* __restrict__ tree,
                                              u16* wpk, u16* uzh, u16* urw, u16* wu, u16* wt2, u16* wov,
                                              u16* uxp2, u16* utp2, u16* embp, u16* tre2) {
  const int i = blockIdx.x * 256 + threadIdx.x;
  const int seg = blockIdx.y;
  u16 h, l;
  if (seg == 0) {  // wpk [768][256] hi+lo: x-side of Wz|Wh|Wr
    if (i >= 196608) return;
    const int row = i >> 8, c = i & 255;
    const float v = (row < 256) ? Wz[row * 512 + c]
                                : (row < 512) ? Wh[(row - 256) * 512 + c] : Wr[(row - 512) * 256 + c];
    split2(v, h, l); wpk[i] = h; wpk[196608 + i] = l;
  } else if (seg == 1) {  // uzh [512][256] hi only: m-side of Wz|Wh
    if (i >= 131072) return;
    const int row = i >> 8, c = i & 255;
    const float v = (row < 256) ? Wz[row * 512 + 256 + c] : Wh[(row - 256) * 512 + 256 + c];
    uzh[i] = f2b(v);
  } else if (seg == 2) {  // urw [256][256] hi only
    if (i >= 65536) return;
    urw[i] = f2b(Ur[i]);
  } else if (seg == 3) {  // wu rows 0-255 = Ww[:, :256] hi; wt2 [2][256][64] split
    if (i >= 81920) return;
    if (i < 65536) {
      const int row = i >> 8, c = i & 255;
      wu[i] = f2b(Ww[row * 320 + c]);
    } else {
      const int j = i - 65536, row = j >> 6, c = j & 63;
      split2(Ww[row * 320 + 256 + c], h, l); wt2[j] = h; wt2[16384 + j] = l;
    }
  } else if (seg == 4) {  // wov [896][256] hi only, rows 800.. zero
    if (i >= 229376) return;
    const float v = (i < 204800) ? Wo[i] : 0.f;
    wov[i] = f2b(v);
  } else if (seg == 5) {  // uxp2 split; wu rows 256-511 = Uw[:,256:512] hi; utp2 split
    if (i >= 147456) return;
    if (i < 65536) {
      const int row = i >> 8, c = i & 255;
      split2(Uw[row * 576 + c], h, l); uxp2[i] = h; uxp2[65536 + i] = l;
    } else if (i < 131072) {
      const int j = i - 65536, row = j >> 8, c = j & 255;
      wu[65536 + j] = f2b(Uw[row * 576 + 256 + c]);
    } else {
      const int j = i - 131072, row = j >> 6, c = j & 63;
      split2(Uw[row * 576 + 512 + c], h, l); utp2[j] = h; utp2[16384 + j] = l;
    }
  } else if (seg == 6) {  // embp [2][896][256] split, rows 800.. zero
    if (i >= 229376) return;
    const int row = i >> 8;
    const float v = (row < 800) ? emb[i] : 0.f;
    split2(v, h, l); embp[i] = h; embp[229376 + i] = l;
  } else {  // tre2 [2][4096][64] split
    if (i >= 65536) return;
    const int b = i >> 4, c4 = (i & 15) << 2;
    const f4 tv = *(const f4*)(tree + (size_t)b * 64 + c4);
    u16x4 hi, lo;
#pragma unroll
    for (int k = 0; k < 4; ++k) { u16 hh, ll; split2(tv[k], hh, ll); hi[k] = hh; lo[k] = ll; }
    *(u16x4*)(tre2 + (size_t)b * 64 + c4) = hi;
    *(u16x4*)(tre2 + 262144 + (size_t)b * 64 + c4) = lo;
  }
}

// ---------------- prep: 4 split GEMMs in one launch -----------------------------------
__global__ __launch_bounds__(256) void k_prep(const u16* __restrict__ embp, const u16* __restrict__ wpk,
                                              const u16* __restrict__ tre2, const u16* __restrict__ wt2,
                                              const u16* __restrict__ utp2, const u16* __restrict__ uxp2,
                                              u16* __restrict__ Aembh, float* __restrict__ Tq,
                                              float* __restrict__ Tp, float* __restrict__ Xp) {
  __shared__ u16 sm[16384];
  f32x4 acc[16] = {};
  const int bid = blockIdx.x;
  int seg, bx, by, K;
  const u16 *A0, *B0;
  size_t Aoff, Boff;
  if (bid < 42) { seg = 0; bx = bid % 7; by = bid / 7; A0 = embp; Aoff = 229376; B0 = wpk; Boff = 196608; K = 256; }
  else if (bid < 106) { const int l2 = bid - 42; seg = 1; bx = l2 % 32; by = l2 / 32; A0 = tre2; Aoff = 262144; B0 = wt2; Boff = 16384; K = 64; }
  else if (bid < 170) { const int l2 = bid - 106; seg = 2; bx = l2 % 32; by = l2 / 32; A0 = tre2; Aoff = 262144; B0 = utp2; Boff = 16384; K = 64; }
  else { const int l2 = bid - 170; seg = 3; bx = l2 % 7; by = l2 / 7; A0 = embp; Aoff = 229376; B0 = uxp2; Boff = 65536; K = 256; }
  A0 += (size_t)bx * 128 * K;
  B0 += (size_t)by * 128 * K;
  mm128<2, 2, true, true>(A0, A0 + Aoff, B0, B0 + Boff, K, sm, acc);
  const int lane = threadIdx.x & 63, wv = threadIdx.x >> 6;
  const int wr = wv >> 1, wc = wv & 1, quad = lane >> 4, c = lane & 15;
#pragma unroll
  for (int i = 0; i < 4; ++i)
#pragma unroll
    for (int j = 0; j < 4; ++j)
#pragma unroll
      for (int rg = 0; rg < 4; ++rg) {
        const size_t row = (size_t)bx * 128 + wr * 64 + i * 16 + quad * 4 + rg;
        const int col = by * 128 + wc * 64 + j * 16 + c;
        const float v = acc[i * 4 + j][rg];
        if (seg == 0) Aembh[row * 768 + col] = f2b(v);
        else if (seg == 1) Tq[row * 256 + col] = v;
        else if (seg == 2) Tp[row * 256 + col] = v;
        else Xp[row * 256 + col] = v;
      }
}

// ---------------- fused GRU scan: 256 blocks x 1024 thr (R10 form) --------------------
__global__ __launch_bounds__(1024, 1) void k_scan(const u16* __restrict__ uzh, const u16* __restrict__ urw,
                                                  const u16* __restrict__ Aembh, const int* __restrict__ wid,
                                                  const float* __restrict__ Wz_b, const float* __restrict__ Wh_b,
                                                  const float* __restrict__ Ur_b,
                                                  u16* __restrict__ mfh, u16* __restrict__ mrh) {
  __shared__ __align__(16) u16 MH[8192];
  __shared__ __align__(16) u16 ML[8192];
  __shared__ __align__(16) u16 RH[8192];
  __shared__ __align__(16) u16 RL[8192];
  const int tid = threadIdx.x;
  const int wv = tid >> 6, lane = tid & 63;
  const int l15 = lane & 15, quad = lane >> 4;
  const int r0 = blockIdx.x * 32;
  const int dir = r0 >> 12;
  const int b0 = r0 & 4095;
  for (int i = tid; i < 8192; i += 1024) { MH[i] = 0; ML[i] = 0; RH[i] = 0; RL[i] = 0; }
  const int zc0 = wv * 16;
  const int cc = zc0 + l15;
  const float bzv = Wz_b[cc], bhv = Wh_b[cc], urv = Ur_b[cc];
  // step-invariant weight fragments -> VGPRs
  s16x8 wz[8], wh[8];
#pragma unroll
  for (int kc = 0; kc < 8; ++kc) {
    const size_t zo = (size_t)cc * 256 + kc * 32 + quad * 8;
    wz[kc] = *(const s16x8*)(uzh + zo);
    wh[kc] = *(const s16x8*)(uzh + zo + 65536);
  }
  float mnew[2][4];
  __syncthreads();
  for (int s = 0; s < 15; ++s) {
    const int tsrc = dir ? (15 - s) : s;
    const int tdst = dir ? (14 - s) : (s + 1);
    int xids[8], xds[8];
#pragma unroll
    for (int mt = 0; mt < 2; ++mt)
#pragma unroll
      for (int rg = 0; rg < 4; ++rg) {
        const int b = b0 + mt * 16 + quad * 4 + rg;
        xids[mt * 4 + rg] = wid[b * 16 + tsrc];
        xds[mt * 4 + rg] = (s < 14) ? wid[b * 16 + tdst] : 0;
      }
    f32x4 aZ[2] = {};
    f32x4 aH[2] = {};
    for (int kc = 0; kc < 8; ++kc) {
      s16x8 amh[2], aml[2], arh[2], arl[2];
#pragma unroll
      for (int mt = 0; mt < 2; ++mt) {
        const int ai = ((kc * 4 + quad) * 32 + mt * 16 + l15) * 8;
        amh[mt] = *(const s16x8*)&MH[ai];
        aml[mt] = *(const s16x8*)&ML[ai];
        arh[mt] = *(const s16x8*)&RH[ai];
        arl[mt] = *(const s16x8*)&RL[ai];
      }
#pragma unroll
      for (int mt = 0; mt < 2; ++mt) {
        aZ[mt] = MFMA(amh[mt], wz[kc], aZ[mt]);
        aZ[mt] = MFMA(aml[mt], wz[kc], aZ[mt]);
        aH[mt] = MFMA(arh[mt], wh[kc], aH[mt]);
        aH[mt] = MFMA(arl[mt], wh[kc], aH[mt]);
      }
    }
    __syncthreads();
#pragma unroll
    for (int mt = 0; mt < 2; ++mt)
#pragma unroll
      for (int rg = 0; rg < 4; ++rg) {
        const int rr = mt * 16 + quad * 4 + rg;
        const int xid = xids[mt * 4 + rg];
        const int mi = ((cc >> 3) * 32 + rr) * 8 + (cc & 7);
        const float az = b2f(Aembh[(size_t)xid * 768 + cc]);
        const float ah = b2f(Aembh[(size_t)xid * 768 + 256 + cc]);
        const float mp = b2f(MH[mi]) + b2f(ML[mi]);
        const float z = fsig(aZ[mt][rg] + az + bzv);
        const float ht = ftanh(aH[mt][rg] + ah + bhv);
        const float mv = (1.f - z) * mp + z * ht;
        mnew[mt][rg] = mv;
        u16 hh, ll; split2(mv, hh, ll);
        MH[mi] = hh; ML[mi] = ll;
      }
    __syncthreads();
    {
      u16* dst = dir ? (mrh + ((size_t)(14 - s) * 4096 + b0) * 256)
                     : (mfh + ((size_t)s * 4096 + b0) * 256);
      const int r = tid >> 5, cg = tid & 31;
      const s16x8 v = *(const s16x8*)&MH[(cg * 32 + r) * 8];
      *(s16x8*)(dst + r * 256 + cg * 8) = v;
    }
    if (s == 14) break;
    f32x4 aR[2] = {};
    for (int kc = 0; kc < 8; ++kc) {
      s16x8 amh[2], aml[2];
#pragma unroll
      for (int mt = 0; mt < 2; ++mt) {
        const int ai = ((kc * 4 + quad) * 32 + mt * 16 + l15) * 8;
        amh[mt] = *(const s16x8*)&MH[ai];
        aml[mt] = *(const s16x8*)&ML[ai];
      }
      const size_t ro = (size_t)cc * 256 + kc * 32 + quad * 8;
      const s16x8 brh = *(const s16x8*)(urw + ro);
#pragma unroll
      for (int mt = 0; mt < 2; ++mt) {
        aR[mt] = MFMA(amh[mt], brh, aR[mt]);
        aR[mt] = MFMA(aml[mt], brh, aR[mt]);
      }
    }
#pragma unroll
    for (int mt = 0; mt < 2; ++mt)
#pragma unroll
      for (int rg = 0; rg < 4; ++rg) {
        const int rr = mt * 16 + quad * 4 + rg;
        const int xd = xds[mt * 4 + rg];
        const int mi = ((cc >> 3) * 32 + rr) * 8 + (cc & 7);
        const float ar = b2f(Aembh[(size_t)xd * 768 + 512 + cc]);
        const float rp = aR[mt][rg] + ar + urv;
        const float rmv = fsig(rp) * mnew[mt][rg];
        u16 hh, ll; split2(rmv, hh, ll);
        RH[mi] = hh; RL[mi] = ll;
      }
    __syncthreads();
  }
}

// ---------------- mid: heads1 (q1 + pH-fwd fused GEMM) + build_hrev + roots -----------
__global__ __launch_bounds__(256) void k_mid(const u16* __restrict__ mfh, const u16* __restrict__ mrh,
                                             const u16* __restrict__ wu,
                                             const float* __restrict__ Tq, const float* __restrict__ W_b,
                                             const float* __restrict__ Xp, const float* __restrict__ Tp,
                                             const float* __restrict__ U_b, const float* __restrict__ Us_w,
                                             const int* __restrict__ wid,
                                             u16* __restrict__ hq, u16* __restrict__ hrev,
                                             float* __restrict__ ppart) {
  const int bid = blockIdx.x;
  const int tid = threadIdx.x;
  if (bid < 1920) {
    __shared__ u16 sm[8192];
    f32x4 acc[16] = {};
    const int rb = bid >> 2, ct = bid & 3;
    const u16* Ah = mfh + (size_t)rb * 128 * 256;
    const u16* Bh = wu + (size_t)ct * 128 * 256;
    mm128<4, 1, false, false>(Ah, nullptr, Bh, nullptr, 256, sm, acc);
    const int lane = tid & 63, wv = tid >> 6, quad = lane >> 4, c = lane & 15;
    if (ct < 2) {
      const int colb = ct * 128;
#pragma unroll
      for (int i = 0; i < 2; ++i)
#pragma unroll
        for (int rg = 0; rg < 4; ++rg) {
          const size_t row = (size_t)rb * 128 + wv * 32 + i * 16 + quad * 4 + rg;
          const int b = (int)(row & 4095);
#pragma unroll
          for (int j = 0; j < 8; ++j) {
            const int col = colb + j * 16 + c;
            const float hv = fmaxf(acc[i * 8 + j][rg] + Tq[(size_t)b * 256 + col] + W_b[col], 0.f);
            hq[(row + 4096) * 256 + col] = f2b(hv);
          }
        }
    } else {
      const int colb = (ct - 2) * 128;
#pragma unroll
      for (int i = 0; i < 2; ++i)
#pragma unroll
        for (int rg = 0; rg < 4; ++rg) {
          const size_t row = (size_t)rb * 128 + wv * 32 + i * 16 + quad * 4 + rg;
          const int t = (int)(row >> 12), b = (int)(row & 4095);
          const int xid = wid[b * 16 + t + 1];
          const int prow = (int)row + 4096;
          float d = 0.f;
#pragma unroll
          for (int j = 0; j < 8; ++j) {
            const int col = colb + j * 16 + c;
            float h = acc[i * 8 + j][rg] + Xp[(size_t)xid * 256 + col] + Tp[(size_t)b * 256 + col] + U_b[col];
            h = fmaxf(h, 0.f);
            d += h * Us_w[col];
          }
#pragma unroll
          for (int dd = 1; dd < 16; dd <<= 1) d += __shfl_xor(d, dd);
          if (c == 0) ppart[(size_t)prow * 2 + (ct - 2)] = d;
        }
    }
  } else if (bid < 9600) {
    const int idx = (bid - 1920) * 256 + tid;  // < 61440*32
    const int r = idx >> 5, g8 = idx & 31;
    const int t = r >> 12;
    const size_t o = (size_t)r * 256 + g8 * 8;
    const u16x8 a = *(const u16x8*)(mrh + o);
    u16x8 out = a;
    if (t > 0) {
      const u16x8 a2 = *(const u16x8*)(mfh + o - 1048576);
#pragma unroll
      for (int k = 0; k < 8; ++k) out[k] = f2b(b2f(a[k]) + b2f(a2[k]));
    }
    *(u16x8*)(hrev + o) = out;
  } else {
    const int b = bid - 9600;  // < 4096
    const int col = tid;
    const float hv = fmaxf(Tq[(size_t)b * 256 + col] + W_b[col], 0.f);
    hq[(size_t)b * 256 + col] = f2b(hv);
    const int xid = wid[b * 16];
    float d = fmaxf(Xp[(size_t)xid * 256 + col] + Tp[(size_t)b * 256 + col] + U_b[col], 0.f) * Us_w[col];
#pragma unroll
    for (int dd = 1; dd < 64; dd <<= 1) d += __shfl_xor(d, dd);
    __shared__ float red[4];
    if ((tid & 63) == 0) red[tid >> 6] = d;
    __syncthreads();
    if (tid == 0) {
      ppart[(size_t)b * 2] = red[0] + red[1] + red[2] + red[3];
      ppart[(size_t)b * 2 + 1] = 0.f;
    }
  }
}

// ---------------- tail: q2 A-resident (512 blocks, 7 Wo tiles streamed) + pH-rev ------
__global__ __launch_bounds__(256) void k_tail(const u16* __restrict__ hq, const u16* __restrict__ wov,
                                              const u16* __restrict__ wu, const u16* __restrict__ hrev,
                                              const float* __restrict__ Wo_b, const float* __restrict__ Xp,
                                              const float* __restrict__ Tp, const float* __restrict__ U_b,
                                              const float* __restrict__ Us_w, const int* __restrict__ wid,
                                              float* __restrict__ qpart, float* __restrict__ ppart) {
  __shared__ __align__(16) u16 smem[40960];  // 80 KB: q2 uses A 64KB + B dbuf 16KB; pH-rev uses first 16KB
  const int bid = blockIdx.x;
  const int tid = threadIdx.x, lane = tid & 63, wv = tid >> 6;
  const int quad = lane >> 4, c = lane & 15;
  if (bid < 512) {
    char* LA = (char*)smem;              // 8 chunks x [128 rows][64B]
    char* LB = (char*)(smem + 32768);    // 2 x 8KB dbuf
    const u16* Ah = hq + (size_t)bid * 128 * 256;
    const size_t soff = (size_t)(tid >> 2) * 512 + (size_t)((tid & 3) * 16);
    // stage A tile once (8 chunks x 2 gld16)
#pragma unroll
    for (int kt = 0; kt < 8; ++kt) {
      gld16((const char*)Ah + soff + kt * 64, LA + kt * 8192 + wv * 1024);
      gld16((const char*)Ah + soff + 32768 + kt * 64, LA + kt * 8192 + 4096 + wv * 1024);
    }
    // stage B chunk 0 of tile 0
    gld16((const char*)wov + soff, LB + wv * 1024);
    gld16((const char*)wov + soff + 32768, LB + 4096 + wv * 1024);
    // per-row running softmax state + targets
    float rM[8], rS[8], rSel[8];
    int rAm[8], qts[8];
#pragma unroll
    for (int mt = 0; mt < 2; ++mt)
#pragma unroll
      for (int rg = 0; rg < 4; ++rg) {
        const int r8 = mt * 4 + rg;
        rM[r8] = -1e30f; rS[r8] = 0.f; rSel[r8] = -1e30f; rAm[r8] = 0x7fffffff;
        const size_t row = (size_t)bid * 128 + wv * 32 + mt * 16 + quad * 4 + rg;
        qts[r8] = wid[(row & 4095) * 16 + (int)(row >> 12)];
      }
    f32x4 acc[16];
    for (int nt = 0; nt < 7; ++nt) {
#pragma unroll
      for (int i = 0; i < 16; ++i) acc[i] = (f32x4){0.f, 0.f, 0.f, 0.f};
      for (int kt = 0; kt < 8; ++kt) {
        const int g = nt * 8 + kt;
        __syncthreads();  // chunk g staged & visible; prev buffer free
        if (g < 55) {
          const int nn = (g + 1) >> 3, nk = (g + 1) & 7;
          const char* Bn = (const char*)(wov + (size_t)nn * 32768) + soff + nk * 64;
          gld16(Bn, LB + ((g + 1) & 1) * 8192 + wv * 1024);
          gld16(Bn + 32768, LB + ((g + 1) & 1) * 8192 + 4096 + wv * 1024);
        }
        s16x8 af[2], bf[8];
#pragma unroll
        for (int mt = 0; mt < 2; ++mt)
          af[mt] = *(const s16x8*)(LA + kt * 8192 + (wv * 32 + mt * 16 + c) * 64 + quad * 16);
#pragma unroll
        for (int j = 0; j < 8; ++j)
          bf[j] = *(const s16x8*)(LB + (g & 1) * 8192 + (j * 16 + c) * 64 + quad * 16);
#pragma unroll
        for (int mt = 0; mt < 2; ++mt)
#pragma unroll
          for (int j = 0; j < 8; ++j)
            acc[mt * 8 + j] = MFMA(af[mt], bf[j], acc[mt * 8 + j]);
      }
      // merge this tile's softmax partials into running state
      const int colb = nt * 128;
#pragma unroll
      for (int mt = 0; mt < 2; ++mt)
#pragma unroll
        for (int rg = 0; rg < 4; ++rg) {
          const int r8 = mt * 4 + rg;
          float vals[8];
          float mx = -1e30f;
          int am = 0x7fffffff;
#pragma unroll
          for (int j = 0; j < 8; ++j) {
            const int col = colb + j * 16 + c;
            float v = -1e30f;
            if (col < 800) v = acc[mt * 8 + j][rg] + Wo_b[col];
            vals[j] = v;
            if (v > mx) { mx = v; am = col; }
          }
          float gm = mx;
          int ga = am;
#pragma unroll
          for (int d = 1; d < 16; d <<= 1) {
            const float om = __shfl_xor(gm, d);
            const int oa = __shfl_xor(ga, d);
            if (om > gm || (om == gm && oa < ga)) { gm = om; ga = oa; }
          }
          float s = 0.f, sel = -1e30f;
#pragma unroll
          for (int j = 0; j < 8; ++j) {
            s += __expf(vals[j] - gm);
            if (colb + j * 16 + c == qts[r8]) sel = vals[j];
          }
#pragma unroll
          for (int d = 1; d < 16; d <<= 1) {
            s += __shfl_xor(s, d);
            sel = fmaxf(sel, __shfl_xor(sel, d));
          }
          const float oM = rM[r8];
          if (gm > oM || (gm == oM && ga < rAm[r8])) rAm[r8] = ga;
          const float nM = fmaxf(oM, gm);
          rS[r8] = rS[r8] * __expf(oM - nM) + s * __expf(gm - nM);
          rM[r8] = nM;
          rSel[r8] = fmaxf(rSel[r8], sel);
        }
    }
    if (c == 0) {
#pragma unroll
      for (int mt = 0; mt < 2; ++mt)
#pragma unroll
        for (int rg = 0; rg < 4; ++rg) {
          const int r8 = mt * 4 + rg;
          const size_t row = (size_t)bid * 128 + wv * 32 + mt * 16 + quad * 4 + rg;
          f4 o;
          o.x = rM[r8]; o.y = rS[r8]; o.z = (float)rAm[r8]; o.w = rSel[r8];
          *(f4*)(qpart + row * 4) = o;
        }
    }
  } else {
    f32x4 acc[16] = {};
    const int l2 = bid - 512;
    const int by = l2 & 1, bx = l2 >> 1;
    const u16* Ah = hrev + (size_t)bx * 128 * 256;
    const u16* Bh = wu + (size_t)(256 + by * 128) * 256;
    mm128<4, 1, false, false>(Ah, nullptr, Bh, nullptr, 256, smem, acc);
    const int colb = by * 128;
#pragma unroll
    for (int i = 0; i < 2; ++i)
#pragma unroll
      for (int rg = 0; rg < 4; ++rg) {
        const size_t row = (size_t)bx * 128 + wv * 32 + i * 16 + quad * 4 + rg;
        const int t = (int)(row >> 12), b = (int)(row & 4095);
        const int xid = wid[b * 16 + t];
        const int prow = (30 - t) * 4096 + b;
        float d = 0.f;
#pragma unroll
        for (int j = 0; j < 8; ++j) {
          const int col = colb + j * 16 + c;
          float h = acc[i * 8 + j][rg] + Xp[(size_t)xid * 256 + col] + Tp[(size_t)b * 256 + col] + U_b[col];
          h = fmaxf(h, 0.f);
          d += h * Us_w[col];
        }
#pragma unroll
        for (int dd = 1; dd < 16; dd <<= 1) d += __shfl_xor(d, dd);
        if (c == 0) ppart[(size_t)prow * 2 + by] = d;
      }
  }
}

// ---------------- reduce: q (per-row final) + p (logistic loss) -----------------------
__global__ __launch_bounds__(256) void k_red(const float* __restrict__ qpart, const float* __restrict__ ppart,
                                             const int* __restrict__ wid, const float* __restrict__ Us_b,
                                             float* __restrict__ accb) {
  __shared__ float s0, s1;
  if (threadIdx.x == 0) { s0 = 0.f; s1 = 0.f; }
  __syncthreads();
  if (blockIdx.x < 256) {
    const int r = blockIdx.x * 256 + threadIdx.x;  // < 65536
    const f4 p4 = *(const f4*)(qpart + (size_t)r * 4);
    const float logZ = p4.x + logf(p4.y);
    const int am = (int)p4.z;
    const int t = r >> 12, b = r & 4095;
    const int qt = wid[b * 16 + t];
    atomicAdd(&s0, logZ - p4.w);
    atomicAdd(&s1, (am == qt) ? 1.f : 0.f);
    __syncthreads();
    if (threadIdx.x == 0) {
      atomicAdd(&accb[blockIdx.x & 15], s0);
      atomicAdd(&accb[16 + (blockIdx.x & 15)], s1);
    }
  } else {
    const int r = (blockIdx.x - 256) * 256 + threadIdx.x;  // < 126976
    const float p = ppart[(size_t)r * 2] + ppart[(size_t)r * 2 + 1] + Us_b[0];
    const int sidx = r >> 12;
    const float pt = (sidx < 15) ? 1.f : 0.f;
    const float loss = fmaxf(p, 0.f) + log1pf(expf(-fabsf(p))) - p * pt;
    const float hit = ((p > 0.f) == (pt > 0.5f)) ? 1.f : 0.f;
    atomicAdd(&s0, loss);
    atomicAdd(&s1, hit);
    __syncthreads();
    if (threadIdx.x == 0) {
      atomicAdd(&accb[32 + (blockIdx.x & 15)], s0);
      atomicAdd(&accb[48 + (blockIdx.x & 15)], s1);
    }
  }
}

__global__ void k_finalize(const float* __restrict__ accb, float* __restrict__ out) {
  if (threadIdx.x == 0 && blockIdx.x == 0) {
    float ql = 0, qa = 0, pl = 0, pa = 0;
    for (int i = 0; i < 16; ++i) {
      ql += accb[i];
      qa += accb[16 + i];
      pl += accb[32 + i];
      pa += accb[48 + i];
    }
    out[0] = ql / 4096.f;
    out[1] = pl / 4096.f;
    out[2] = qa / 65536.f;
    out[3] = pa / 126976.f;
  }
}

__global__ void k_flag(float* __restrict__ out) {
  if (threadIdx.x < 4) out[threadIdx.x] = -12345.f;  // ws_size-too-small sentinel
}

// ---------------- host launch ---------------------------------------------------------
extern "C" void kernel_launch(void* const* d_in, const int* in_sizes, int n_in,
                              void* d_out, int out_size, void* d_ws, size_t ws_size,
                              hipStream_t stream) {
  (void)in_sizes; (void)n_in; (void)out_size;
  const int* wid = (const int*)d_in[0];
  const float* tree = (const float*)d_in[1];
  const float* emb = (const float*)d_in[2];
  const float* Wz_w = (const float*)d_in[3];
  const float* Wz_b = (const float*)d_in[4];
  const float* Wr_w = (const float*)d_in[5];
  const float* Ur_w = (const float*)d_in[6];
  const float* Ur_b = (const float*)d_in[7];
  const float* Wh_w = (const float*)d_in[8];
  const float* Wh_b = (const float*)d_in[9];
  const float* W_w = (const float*)d_in[10];
  const float* W_b = (const float*)d_in[11];
  const float* U_w = (const float*)d_in[12];
  const float* U_b = (const float*)d_in[13];
  const float* Wo_w = (const float*)d_in[14];
  const float* Wo_b = (const float*)d_in[15];
  const float* Us_w = (const float*)d_in[16];
  const float* Us_b = (const float*)d_in[17];
  char* ws = (char*)d_ws;

  constexpr size_t NEED = 152273152ull;  // ~145.2 MB
  if (ws_size < NEED) {
    k_flag<<<1, 64, 0, stream>>>((float*)d_out);
    return;
  }

  u16* hq = (u16*)(ws + 0ull);                 // [65536][256]
  u16* hrev = (u16*)(ws + 33554432ull);        // [61440][256]
  u16* mfh = (u16*)(ws + 65011712ull);         // [61440][256]
  u16* mrh = (u16*)(ws + 96468992ull);         // [61440][256]
  u16* Aembh = (u16*)(ws + 127926272ull);      // [896][768] hi
  u16* embp = (u16*)(ws + 129302528ull);       // [2][896][256]
  u16* wpk = (u16*)(ws + 130220032ull);        // [2][768][256]
  u16* uzh = (u16*)(ws + 131006464ull);        // [512][256] hi
  u16* urw = (u16*)(ws + 131268608ull);        // [256][256] hi
  u16* wu = (u16*)(ws + 131399680ull);         // [512][256] hi: Ww | Uh
  u16* wt2 = (u16*)(ws + 131661824ull);        // [2][256][64]
  u16* wov = (u16*)(ws + 131727360ull);        // [896][256] hi
  u16* uxp2 = (u16*)(ws + 132186112ull);       // [2][256][256]
  u16* utp2 = (u16*)(ws + 132448256ull);       // [2][256][64]
  u16* tre2 = (u16*)(ws + 132513792ull);       // [2][4096][64]
  float* Tq = (float*)(ws + 133562368ull);     // [4096][256]
  float* Tp = (float*)(ws + 137756672ull);     // [4096][256]
  float* Xp = (float*)(ws + 141950976ull);     // [896][256]
  float* qpart = (float*)(ws + 142868480ull);  // [65536][4] f4 (1 MB used)
  float* ppart = (float*)(ws + 151257088ull);  // [126976][2]
  float* accb = (float*)(ws + 152272896ull);   // 64 floats

  hipMemsetAsync(accb, 0, 256, stream);

  k_pack<<<dim3(896, 8), 256, 0, stream>>>(Wz_w, Wr_w, Ur_w, Wh_w, W_w, U_w, Wo_w, emb, tree,
                                           wpk, uzh, urw, wu, wt2, wov, uxp2, utp2, embp, tre2);
  k_prep<<<184, 256, 0, stream>>>(embp, wpk, tre2, wt2, utp2, uxp2, Aembh, Tq, Tp, Xp);
  k_scan<<<256, 1024, 0, stream>>>(uzh, urw, Aembh, wid, Wz_b, Wh_b, Ur_b, mfh, mrh);
  k_mid<<<13696, 256, 0, stream>>>(mfh, mrh, wu, Tq, W_b, Xp, Tp, U_b, Us_w, wid, hq, hrev, ppart);
  k_tail<<<1472, 256, 0, stream>>>(hq, wov, wu, hrev, Wo_b, Xp, Tp, U_b, Us_w, wid, qpart, ppart);
  k_red<<<752, 256, 0, stream>>>(qpart, ppart, wid, Us_b, accb);
  k_finalize<<<1, 64, 0, stream>>>(accb, (float*)d_out);
}